// Round 10
// baseline (1774.148 us; speedup 1.0000x reference)
//
#include <hip/hip_runtime.h>
#include <cstdint>
#include <cstddef>

// RNN: B=256, T=512, H=512, I=64, O=24. fp32 in/out.
//
// v10 structure:
//  Path A7 (ws >= 256 MiB, out big enough):
//    1) xp_gemm: xp = W_ih x + b_ih + b_hh (f16, permuted) -> ws[0,128Mi).
//       Block 0 also packs 11 W_hh fragment slots (f16, MFMA layout) into
//       the TAIL OF d_out (88 KB; out_all fully overwrites d_out later).
//    2) rnn_core7: 16 blocks x 8 waves. W_hh 64 slots split across THREE
//       pipes: 50 in regs (200/lane — the hard 256-total boundary, r9),
//       3 in LDS, 11 streamed from L2-resident global (the vmem pipe was
//       idle while LDS carried 240 KB/step). Global slots mapped to the
//       LAST s-slots so post-barrier loads have ~1800cy slack. Split
//       barrier (lgkmcnt only) keeps hall-store acks off the critical path.
//    3) out_all: full-chip epilogue out = tanh(h_all @ W_ho^T + b_ho).
//  Path B: r9 path (962us core, proven). Path C: self-contained fallback.
//
//  Hard constraints learned (measured r0-r9):
//   - Wave reg budget = 256 TOTAL (128 arch + 128 AGPR) at 8 waves/CU;
//     NREG=50 weight slots + ~56 arch = exactly full. 51+ spills (~5us/step).
//   - LDS b128 ~12cy/instr, immune to same-address broadcast (r7).
//   - per-step cross-CU sync = L2 flush ~6us/step -> never (r5).
//   - split barrier (no vmcnt drain) + NREG 49->50: 1005->962us (r9).

#define TSTEPS 512
#define HDIM   512
#define NIN    64
#define NOUT   24
#define BB     16
#define HPAD   520
#define XPAD   72
// weight slot partition (slot id = s*4+m, 64 slots):
#define NLDSL  3                 // ids 0..2      -> LDS
#define NREG   50                // ids 3..52     -> registers
#define NGLB   11                // ids 53..63    -> global (L2-resident)
#define WG_H16 (NGLB * 8 * 64 * 8)     // 45056 h16 = 88 KiB
#define WG_F32 (WG_H16 / 2)            // 22528 floats carved from d_out tail

typedef _Float16 h16;
typedef __attribute__((ext_vector_type(8))) _Float16 h16x8;
typedef __attribute__((ext_vector_type(4))) _Float16 h16x4;
typedef __attribute__((ext_vector_type(2))) _Float16 h16x2;
typedef __attribute__((ext_vector_type(4))) float    f32x4;
typedef __attribute__((ext_vector_type(2))) float    f32x2;

__device__ __forceinline__ float fast_tanh(float z) {
  float e = __builtin_amdgcn_exp2f(z * 2.8853900817779268f);
  return 1.0f - 2.0f * __builtin_amdgcn_rcpf(e + 1.0f);
}

__device__ __forceinline__ h16x8 cvt8(const float* __restrict__ p) {
  f32x4 f0 = *(const f32x4*)p;
  f32x4 f1 = *(const f32x4*)(p + 4);
  h16x8 a;
  #pragma unroll
  for (int j = 0; j < 4; ++j) { a[j] = (h16)f0[j]; a[4 + j] = (h16)f1[j]; }
  return a;
}

// ---------------- Prologue: xp GEMM + (block 0) weight-fragment pack ---------
// xp chunk ((t*16+g)*8+wave)*64+lane holds 16 h16:
// [m*4+i] = xp[batch=16g+(lane&15)][t][col=64*wave+16m+4*(lane>>4)+i]
__global__ __launch_bounds__(512)
void xp_gemm(const float* __restrict__ x, const float* __restrict__ Wih,
             const float* __restrict__ bih, const float* __restrict__ bhh,
             h16* __restrict__ xp, h16* wg, const float* __restrict__ Whh)
{
  const int tid  = threadIdx.x;
  const int wave = tid >> 6;
  const int lane = tid & 63;
  const int lr   = lane & 15;
  const int lk   = lane >> 4;
  const int blk  = blockIdx.x & 15;
  const int tc   = blockIdx.x >> 4;
  const int c0   = wave * 64;

  // pack the 11 global weight slots (same for all batch blocks)
  if (wg && blockIdx.x == 0) {
    #pragma unroll
    for (int j = 0; j < NGLB; ++j) {
      const int id = 53 + j;
      const int s = id >> 2, m = id & 3;
      h16x8 a = cvt8(Whh + (size_t)(c0 + 16 * m + lr) * HDIM + 32 * s + 8 * lk);
      *(h16x8*)&wg[((size_t)(j * 8 + wave) * 64 + lane) * 8] = a;
    }
  }

  h16x8 A[4][2];
  #pragma unroll
  for (int m = 0; m < 4; ++m)
    #pragma unroll
    for (int s = 0; s < 2; ++s)
      A[m][s] = cvt8(Wih + (size_t)(c0 + 16 * m + lr) * NIN + 32 * s + 8 * lk);

  f32x4 bias[4];
  #pragma unroll
  for (int m = 0; m < 4; ++m) {
    const int c = c0 + 16 * m + 4 * lk;
    f32x4 bi = *(const f32x4*)&bih[c];
    f32x4 bh = *(const f32x4*)&bhh[c];
    bias[m] = bi + bh;
  }

  const float* xrow = x + (size_t)(16 * blk + lr) * (TSTEPS * NIN);

  for (int j = 0; j < 32; ++j) {
    const int t = tc * 32 + j;
    f32x4 acc[4];
    #pragma unroll
    for (int m = 0; m < 4; ++m) acc[m] = bias[m];
    #pragma unroll
    for (int s = 0; s < 2; ++s) {
      h16x8 bx = cvt8(xrow + (size_t)t * NIN + 32 * s + 8 * lk);
      #pragma unroll
      for (int m = 0; m < 4; ++m)
        acc[m] = __builtin_amdgcn_mfma_f32_16x16x32_f16(A[m][s], bx, acc[m], 0, 0, 0);
    }
    h16x8 c0v, c1v;
    #pragma unroll
    for (int i = 0; i < 4; ++i) {
      c0v[i]     = (h16)acc[0][i];
      c0v[4 + i] = (h16)acc[1][i];
      c1v[i]     = (h16)acc[2][i];
      c1v[4 + i] = (h16)acc[3][i];
    }
    h16* p = xp + ((((size_t)t * 16 + blk) * 8 + wave) * 64 + lane) * 16;
    *(h16x8*)p       = c0v;
    *(h16x8*)(p + 8) = c1v;
  }
}

// ---------------- Path A7: three-pipe weight stream --------------------------
__global__ __launch_bounds__(512, 2)
void rnn_core7(const float* __restrict__ Whh, const h16* __restrict__ xp,
               h16* __restrict__ hall, const h16* wg)
{
  __shared__ h16 hbuf[2][BB * HPAD];          // 33280 B
  __shared__ h16 aslice[NLDSL * 8 * 512];     // 24576 B -> total 57856 B

  const int tid  = threadIdx.x;
  const int wave = tid >> 6;
  const int lane = tid & 63;
  const int lr   = lane & 15;
  const int lk   = lane >> 4;
  const int blk  = blockIdx.x;
  const int b0   = blk * BB;
  const int wc0  = wave * 64;

  // W_hh fragments: ids 0..2 -> LDS, 3..52 -> regs, 53..63 -> global (packed)
  h16x8 areg[NREG];
  #pragma unroll
  for (int s = 0; s < 16; ++s) {
    #pragma unroll
    for (int m = 0; m < 4; ++m) {
      const int id = s * 4 + m;
      if (id >= NLDSL + NREG) continue;   // global slots: packed by xp_gemm
      h16x8 a = cvt8(Whh + (size_t)(wc0 + 16 * m + lr) * HDIM + 32 * s + 8 * lk);
      if (id < NLDSL)
        *(h16x8*)&aslice[(size_t)(id * 8 + wave) * 512 + lane * 8] = a;
      else
        areg[id - NLDSL] = a;
    }
  }

  for (int idx = tid; idx < BB * HPAD; idx += 512) hbuf[0][idx] = (h16)0.f;
  __syncthreads();

  // per-lane base for the global weight stream
  const h16* wgl = wg + (size_t)(wave * 64 + lane) * 8;

  // preload xp(0)
  h16x8 xr0, xr1;
  {
    const h16* p = xp + (((size_t)blk * 8 + wave) * 64 + lane) * 16;
    xr0 = *(const h16x8*)p;
    xr1 = *(const h16x8*)(p + 8);
  }

  for (int t = 0; t < TSTEPS; ++t) {
    const h16* hb = hbuf[t & 1];
    h16*       hn = hbuf[(t + 1) & 1];

    f32x4 acc[4];
    #pragma unroll
    for (int i = 0; i < 4; ++i) {
      acc[0][i] = (float)xr0[i];
      acc[1][i] = (float)xr0[4 + i];
      acc[2][i] = (float)xr1[i];
      acc[3][i] = (float)xr1[4 + i];
    }
    {
      const int tn = (t + 1 < TSTEPS) ? (t + 1) : t;
      const h16* p = xp + ((((size_t)tn * 16 + blk) * 8 + wave) * 64 + lane) * 16;
      xr0 = *(const h16x8*)p;
      xr1 = *(const h16x8*)(p + 8);
    }

    #pragma unroll
    for (int s = 0; s < 16; ++s) {
      h16x8 bh = *(const h16x8*)&hb[lr * HPAD + 32 * s + 8 * lk];
      #pragma unroll
      for (int m = 0; m < 4; ++m) {
        const int id = s * 4 + m;
        h16x8 a;
        if (id >= NLDSL + NREG)           // L2-resident stream (vmem pipe)
          a = *(const h16x8*)&wgl[(size_t)(id - (NLDSL + NREG)) * 8 * 512];
        else if (id < NLDSL)              // LDS stream
          a = *(const h16x8*)&aslice[(size_t)(id * 8 + wave) * 512 + lane * 8];
        else                              // register-resident
          a = areg[id - NLDSL];
        acc[m] = __builtin_amdgcn_mfma_f32_16x16x32_f16(a, bh, acc[m], 0, 0, 0);
      }
    }

    // h_t = tanh(z): LDS double-buffer write + fire-and-forget hall store
    h16* hrow = hall + ((size_t)t * 256 + b0 + lr) * HDIM + wc0 + lk * 4;
    #pragma unroll
    for (int m = 0; m < 4; ++m) {
      h16x4 hv;
      #pragma unroll
      for (int i = 0; i < 4; ++i) hv[i] = (h16)fast_tanh(acc[m][i]);
      *(h16x4*)&hn[lr * HPAD + wc0 + 16 * m + 4 * lk] = hv;
      *(h16x4*)(hrow + 16 * m) = hv;
    }

    // split barrier: drain LDS only (h handoff), not global stores.
    // "memory" clobber also stops LLVM hoisting the loop-invariant wgl loads
    // into 44 permanently-live registers (the r0 spill mode).
    asm volatile("s_waitcnt lgkmcnt(0)\n\ts_barrier" ::: "memory");
  }
}

// ---------------- Path B core: r9's proven rnn_core6 -------------------------
#define NREG_B 50
#define NLDS_B (64 - NREG_B)
__global__ __launch_bounds__(512, 2)
void rnn_core6(const float* __restrict__ Whh, const h16* __restrict__ xp,
               h16* __restrict__ hall)
{
  __shared__ h16 hbuf[2][BB * HPAD];
  __shared__ h16 aslice[NLDS_B * 8 * 512];

  const int tid  = threadIdx.x;
  const int wave = tid >> 6;
  const int lane = tid & 63;
  const int lr   = lane & 15;
  const int lk   = lane >> 4;
  const int blk  = blockIdx.x;
  const int b0   = blk * BB;
  const int wc0  = wave * 64;

  h16x8 areg[NREG_B];
  #pragma unroll
  for (int s = 0; s < 16; ++s) {
    #pragma unroll
    for (int m = 0; m < 4; ++m) {
      h16x8 a = cvt8(Whh + (size_t)(wc0 + 16 * m + lr) * HDIM + 32 * s + 8 * lk);
      const int id = s * 4 + m;
      if (id < NREG_B) areg[id] = a;
      else *(h16x8*)&aslice[(size_t)((id - NREG_B) * 8 + wave) * 512 + lane * 8] = a;
    }
  }

  for (int idx = tid; idx < BB * HPAD; idx += 512) hbuf[0][idx] = (h16)0.f;
  __syncthreads();

  h16x8 xr0, xr1;
  {
    const h16* p = xp + (((size_t)blk * 8 + wave) * 64 + lane) * 16;
    xr0 = *(const h16x8*)p;
    xr1 = *(const h16x8*)(p + 8);
  }

  for (int t = 0; t < TSTEPS; ++t) {
    const h16* hb = hbuf[t & 1];
    h16*       hn = hbuf[(t + 1) & 1];

    f32x4 acc[4];
    #pragma unroll
    for (int i = 0; i < 4; ++i) {
      acc[0][i] = (float)xr0[i];
      acc[1][i] = (float)xr0[4 + i];
      acc[2][i] = (float)xr1[i];
      acc[3][i] = (float)xr1[4 + i];
    }
    {
      const int tn = (t + 1 < TSTEPS) ? (t + 1) : t;
      const h16* p = xp + ((((size_t)tn * 16 + blk) * 8 + wave) * 64 + lane) * 16;
      xr0 = *(const h16x8*)p;
      xr1 = *(const h16x8*)(p + 8);
    }

    #pragma unroll
    for (int s = 0; s < 16; ++s) {
      h16x8 bh = *(const h16x8*)&hb[lr * HPAD + 32 * s + 8 * lk];
      #pragma unroll
      for (int m = 0; m < 4; ++m) {
        const int id = s * 4 + m;
        h16x8 a = (id < NREG_B)
            ? areg[id]
            : *(const h16x8*)&aslice[(size_t)((id - NREG_B) * 8 + wave) * 512 + lane * 8];
        acc[m] = __builtin_amdgcn_mfma_f32_16x16x32_f16(a, bh, acc[m], 0, 0, 0);
      }
    }

    h16* hrow = hall + ((size_t)t * 256 + b0 + lr) * HDIM + wc0 + lk * 4;
    #pragma unroll
    for (int m = 0; m < 4; ++m) {
      h16x4 hv;
      #pragma unroll
      for (int i = 0; i < 4; ++i) hv[i] = (h16)fast_tanh(acc[m][i]);
      *(h16x4*)&hn[lr * HPAD + wc0 + 16 * m + 4 * lk] = hv;
      *(h16x4*)(hrow + 16 * m) = hv;
    }

    asm volatile("s_waitcnt lgkmcnt(0)\n\ts_barrier" ::: "memory");
  }
}

// ---------------- Epilogue: out = tanh(h_all @ W_ho^T + b_ho) ----------------
__global__ __launch_bounds__(512)
void out_all(const h16* __restrict__ hall, const float* __restrict__ Who,
             const float* __restrict__ bho, float* __restrict__ out)
{
  __shared__ h16 wholds[NOUT * HPAD];   // 24960 B

  const int tid  = threadIdx.x;
  const int wave = tid >> 6;
  const int lane = tid & 63;
  const int lr   = lane & 15;
  const int lk   = lane >> 4;

  for (int idx = tid; idx < NOUT * HDIM; idx += 512) {
    int r = idx >> 9, k = idx & 511;
    wholds[r * HPAD + k] = (h16)Who[idx];
  }

  f32x4 o0, o1;
  { o0 = *(const f32x4*)&bho[lk * 4]; }
  { int ob = 16 + lk * 4;
    if (ob < NOUT) o1 = *(const f32x4*)&bho[ob];
    else { o1[0] = 0.f; o1[1] = 0.f; o1[2] = 0.f; o1[3] = 0.f; } }
  __syncthreads();

  const int rt = blockIdx.x * 8 + wave;
  const int t  = rt >> 4;
  const int b  = (rt & 15) * 16 + lr;
  const int row1 = (16 + lr < NOUT) ? (16 + lr) : (8 + lr);

  const h16* hrow = hall + ((size_t)t * 256 + b) * HDIM + lk * 8;

  #pragma unroll
  for (int s = 0; s < 16; ++s) {
    h16x8 bh = *(const h16x8*)(hrow + 32 * s);
    h16x8 a0 = *(const h16x8*)&wholds[lr * HPAD + s * 32 + lk * 8];
    h16x8 a1 = *(const h16x8*)&wholds[row1 * HPAD + s * 32 + lk * 8];
    o0 = __builtin_amdgcn_mfma_f32_16x16x32_f16(a0, bh, o0, 0, 0, 0);
    o1 = __builtin_amdgcn_mfma_f32_16x16x32_f16(a1, bh, o1, 0, 0, 0);
  }

  float* op = out + ((size_t)b * TSTEPS + t) * NOUT;
  f32x4 v0;
  #pragma unroll
  for (int i = 0; i < 4; ++i) v0[i] = fast_tanh(o0[i]);
  *(f32x4*)(op + lk * 4) = v0;
  if (lk < 2) {
    f32x4 v1;
    #pragma unroll
    for (int i = 0; i < 4; ++i) v1[i] = fast_tanh(o1[i]);
    *(f32x4*)(op + 16 + lk * 4) = v1;
  }
}

// ---------------- Path C: fully self-contained fallback ----------------------
__device__ __forceinline__ void out_proj(
    int t, const h16* __restrict__ hb, const h16* __restrict__ who,
    f32x4 bho0, f32x4 bho1, float* __restrict__ out, int b0, int lr, int lk)
{
  f32x4 o0 = bho0, o1 = bho1;
  const int row1 = (16 + lr < NOUT) ? (16 + lr) : (8 + lr);
  #pragma unroll
  for (int s = 0; s < 16; ++s) {
    h16x8 bh = *(const h16x8*)&hb[lr * HPAD + s * 32 + lk * 8];
    h16x8 a0 = *(const h16x8*)&who[lr * HPAD + s * 32 + lk * 8];
    h16x8 a1 = *(const h16x8*)&who[row1 * HPAD + s * 32 + lk * 8];
    o0 = __builtin_amdgcn_mfma_f32_16x16x32_f16(a0, bh, o0, 0, 0, 0);
    o1 = __builtin_amdgcn_mfma_f32_16x16x32_f16(a1, bh, o1, 0, 0, 0);
  }
  float* op = out + ((size_t)(b0 + lr) * TSTEPS + t) * NOUT;
  f32x4 v0;
  #pragma unroll
  for (int i = 0; i < 4; ++i) v0[i] = fast_tanh(o0[i]);
  *(f32x4*)(op + lk * 4) = v0;
  if (lk < 2) {
    f32x4 v1;
    #pragma unroll
    for (int i = 0; i < 4; ++i) v1[i] = fast_tanh(o1[i]);
    *(f32x4*)(op + 16 + lk * 4) = v1;
  }
}

__global__ __launch_bounds__(512, 2)
void rnn_fused(const float* __restrict__ x,
               const float* __restrict__ Wih,
               const float* __restrict__ Whh,
               const float* __restrict__ bih,
               const float* __restrict__ bhh,
               const float* __restrict__ Who,
               const float* __restrict__ bho,
               float* __restrict__ out)
{
  __shared__ h16 hbuf[2][BB * HPAD];
  __shared__ h16 xbuf[2][BB * XPAD];
  __shared__ h16 wholds[NOUT * HPAD];

  const int tid  = threadIdx.x;
  const int wave = tid >> 6;
  const int lane = tid & 63;
  const int lr   = lane & 15;
  const int lk   = lane >> 4;
  const int b0   = blockIdx.x * BB;
  const int wc0  = wave * 64;

  h16x8 a_rec[4][16];
  #pragma unroll
  for (int m = 0; m < 4; ++m) {
    const int row = wc0 + m * 16 + lr;
    #pragma unroll
    for (int s = 0; s < 16; ++s)
      a_rec[m][s] = cvt8(Whh + (size_t)row * HDIM + s * 32 + lk * 8);
  }
  h16x8 a_ih[4][2];
  #pragma unroll
  for (int m = 0; m < 4; ++m) {
    const int row = wc0 + m * 16 + lr;
    #pragma unroll
    for (int s = 0; s < 2; ++s)
      a_ih[m][s] = cvt8(Wih + (size_t)row * NIN + s * 32 + lk * 8);
  }
  f32x4 biasv[4];
  #pragma unroll
  for (int m = 0; m < 4; ++m) {
    const int c = wc0 + m * 16 + lk * 4;
    f32x4 bi = *(const f32x4*)&bih[c];
    f32x4 bh2 = *(const f32x4*)&bhh[c];
    biasv[m] = bi + bh2;
  }
  f32x4 bho0, bho1;
  { bho0 = *(const f32x4*)&bho[lk * 4]; }
  { int ob = 16 + lk * 4;
    if (ob < NOUT) bho1 = *(const f32x4*)&bho[ob];
    else { bho1[0] = 0.f; bho1[1] = 0.f; bho1[2] = 0.f; bho1[3] = 0.f; } }

  for (int idx = tid; idx < NOUT * HDIM; idx += 512) {
    int r = idx >> 9, k = idx & 511;
    wholds[r * HPAD + k] = (h16)Who[idx];
  }
  for (int idx = tid; idx < BB * HPAD; idx += 512) hbuf[0][idx] = (h16)0.f;
  {
    int r = tid >> 5, c2 = (tid & 31) * 2;
    f32x2 v = *(const f32x2*)(x + ((size_t)(b0 + r) * TSTEPS + 0) * NIN + c2);
    h16x2 pk = { (h16)v.x, (h16)v.y };
    *(h16x2*)&xbuf[0][r * XPAD + c2] = pk;
  }
  __syncthreads();

  for (int t = 0; t < TSTEPS; ++t) {
    const h16* hb = hbuf[t & 1];
    h16*       hn = hbuf[(t + 1) & 1];
    const h16* xb = xbuf[t & 1];
    h16*       xn = xbuf[(t + 1) & 1];

    if (t > 0 && wave == ((t - 1) & 7))
      out_proj(t - 1, hb, wholds, bho0, bho1, out, b0, lr, lk);

    const int tl = (t + 1 < TSTEPS) ? (t + 1) : (TSTEPS - 1);
    const int xr = tid >> 5, xc = (tid & 31) * 2;
    f32x2 xv = *(const f32x2*)(x + ((size_t)(b0 + xr) * TSTEPS + tl) * NIN + xc);

    f32x4 acc[4];
    #pragma unroll
    for (int m = 0; m < 4; ++m) acc[m] = biasv[m];
    #pragma unroll
    for (int s = 0; s < 2; ++s) {
      h16x8 bx = *(const h16x8*)&xb[lr * XPAD + s * 32 + lk * 8];
      #pragma unroll
      for (int m = 0; m < 4; ++m)
        acc[m] = __builtin_amdgcn_mfma_f32_16x16x32_f16(a_ih[m][s], bx, acc[m], 0, 0, 0);
    }
    #pragma unroll
    for (int s = 0; s < 16; ++s) {
      h16x8 bh = *(const h16x8*)&hb[lr * HPAD + 32 * s + 8 * lk];
      #pragma unroll
      for (int m = 0; m < 4; ++m)
        acc[m] = __builtin_amdgcn_mfma_f32_16x16x32_f16(a_rec[m][s], bh, acc[m], 0, 0, 0);
    }
    #pragma unroll
    for (int m = 0; m < 4; ++m) {
      h16x4 hv;
      #pragma unroll
      for (int i = 0; i < 4; ++i) hv[i] = (h16)fast_tanh(acc[m][i]);
      *(h16x4*)&hn[lr * HPAD + wc0 + 16 * m + 4 * lk] = hv;
    }
    {
      h16x2 pk = { (h16)xv.x, (h16)xv.y };
      *(h16x2*)&xn[xr * XPAD + xc] = pk;
    }
    __syncthreads();
  }

  if (wave == ((TSTEPS - 1) & 7))
    out_proj(TSTEPS - 1, hbuf[TSTEPS & 1], wholds, bho0, bho1, out, b0, lr, lk);
}

extern "C" void kernel_launch(void* const* d_in, const int* in_sizes, int n_in,
                              void* d_out, int out_size, void* d_ws, size_t ws_size,
                              hipStream_t stream) {
  (void)in_sizes; (void)n_in;
  const float* x   = (const float*)d_in[0];
  const float* Wih = (const float*)d_in[1];
  const float* Whh = (const float*)d_in[2];
  const float* bih = (const float*)d_in[3];
  const float* bhh = (const float*)d_in[4];
  const float* Who = (const float*)d_in[5];
  const float* bho = (const float*)d_in[6];
  float* out = (float*)d_out;

  const size_t XP_BYTES   = (size_t)TSTEPS * 256 * HDIM * sizeof(h16);  // 128 MiB
  const size_t HALL_BYTES = (size_t)TSTEPS * 256 * HDIM * sizeof(h16);  // 128 MiB

  if (ws_size >= XP_BYTES + HALL_BYTES) {
    h16* xp   = (h16*)d_ws;
    h16* hall = (h16*)((char*)d_ws + XP_BYTES);
    // wg lives in the tail of d_out (out_all overwrites all of d_out later);
    // needs 16B alignment and room.
    const bool wg_ok = (out_size >= 2 * WG_F32) && ((out_size & 3) == 0);
    if (wg_ok) {
      h16* wg = (h16*)(out + ((size_t)out_size - WG_F32));
      xp_gemm<<<dim3(256), dim3(512), 0, stream>>>(x, Wih, bih, bhh, xp, wg, Whh);
      rnn_core7<<<dim3(16), dim3(512), 0, stream>>>(Whh, xp, hall, wg);
    } else {
      xp_gemm<<<dim3(256), dim3(512), 0, stream>>>(x, Wih, bih, bhh, xp, nullptr, Whh);
      rnn_core6<<<dim3(16), dim3(512), 0, stream>>>(Whh, xp, hall);
    }
    out_all<<<dim3(1024), dim3(512), 0, stream>>>(hall, Who, bho, out);
  } else {
    rnn_fused<<<dim3(256 / BB), dim3(512), 0, stream>>>(x, Wih, Whh, bih, bhh, Who, bho, out);
  }
}

// Round 11
// 971.543 us; speedup vs baseline: 1.8261x; 1.8261x over previous
//
#include <hip/hip_runtime.h>
#include <cstdint>
#include <cstddef>

// RNN: B=256, T=512, H=512, I=64, O=24. fp32 in/out.
//
// v11 structure (revert to r9's proven path + tail refinement):
//  Path A (ws >= 256 MiB):
//    1) xp_gemm: xp = W_ih x + b_ih + b_hh (f16, permuted) -> ws[0,128Mi)
//    2) rnn_core8: 16 blocks x 8 waves, BB=16. W_hh: 50 slots in regs
//       (200/lane; 256-total wave budget is exactly full) + 14 slots in LDS.
//       Split barrier (lgkmcnt only). NEW vs r9: final s-iteration peeled
//       and interleaved per-m (mfma -> tanh -> ds_write pipelined) so the
//       tanh/write tail overlaps MFMA latency; xp/hall addressing
//       strength-reduced to pointer increments (no t-clamp; the t=512
//       prefetch over-read lands in hall, loaded-but-unused).
//    3) out_all: full-chip epilogue out = tanh(h_all @ W_ho^T + b_ho).
//  Fallback: self-contained kernel (~4.4 ms).
//
//  Constraint ledger (measured r0-r10):
//   - Wave budget = 256 regs TOTAL (128 arch + 128 AGPR) at 8 waves/CU.
//     NREG=50 + ~56 arch = full. Anything more spills -> ~5us/step
//     (r0/r6/r8). Explicit AGPR pinning does not bypass it (r8).
//   - Weight stream lives in regs or LDS only: L2-resident global loads
//     expose ~320cy latency each without prefetch regs (r10).
//   - LDS b128 cost is per-instruction (~12cy), immune to same-address
//     broadcast (r7).
//   - Per-step cross-CU sync = L2 flush ~6us/step -> never (r5).
//   - Split barrier (no vmcnt drain): 1005 -> 962us (r9).

#define TSTEPS 512
#define HDIM   512
#define NIN    64
#define NOUT   24
#define BB     16
#define HPAD   520
#define XPAD   72
#define NREG   50
#define NLDS   (64 - NREG)   // 14

typedef _Float16 h16;
typedef __attribute__((ext_vector_type(8))) _Float16 h16x8;
typedef __attribute__((ext_vector_type(4))) _Float16 h16x4;
typedef __attribute__((ext_vector_type(2))) _Float16 h16x2;
typedef __attribute__((ext_vector_type(4))) float    f32x4;
typedef __attribute__((ext_vector_type(2))) float    f32x2;

__device__ __forceinline__ float fast_tanh(float z) {
  float e = __builtin_amdgcn_exp2f(z * 2.8853900817779268f);
  return 1.0f - 2.0f * __builtin_amdgcn_rcpf(e + 1.0f);
}

__device__ __forceinline__ h16x8 cvt8(const float* __restrict__ p) {
  f32x4 f0 = *(const f32x4*)p;
  f32x4 f1 = *(const f32x4*)(p + 4);
  h16x8 a;
  #pragma unroll
  for (int j = 0; j < 4; ++j) { a[j] = (h16)f0[j]; a[4 + j] = (h16)f1[j]; }
  return a;
}

// ---------------- Prologue: xp = W_ih x + b_ih + b_hh, permuted f16 ----------
// chunk ((t*16+g)*8+wave)*64+lane holds 16 h16:
// [m*4+i] = xp[batch=16g+(lane&15)][t][col=64*wave+16m+4*(lane>>4)+i]
__global__ __launch_bounds__(512)
void xp_gemm(const float* __restrict__ x, const float* __restrict__ Wih,
             const float* __restrict__ bih, const float* __restrict__ bhh,
             h16* __restrict__ xp)
{
  const int tid  = threadIdx.x;
  const int wave = tid >> 6;
  const int lane = tid & 63;
  const int lr   = lane & 15;
  const int lk   = lane >> 4;
  const int blk  = blockIdx.x & 15;
  const int tc   = blockIdx.x >> 4;
  const int c0   = wave * 64;

  h16x8 A[4][2];
  #pragma unroll
  for (int m = 0; m < 4; ++m)
    #pragma unroll
    for (int s = 0; s < 2; ++s)
      A[m][s] = cvt8(Wih + (size_t)(c0 + 16 * m + lr) * NIN + 32 * s + 8 * lk);

  f32x4 bias[4];
  #pragma unroll
  for (int m = 0; m < 4; ++m) {
    const int c = c0 + 16 * m + 4 * lk;
    f32x4 bi = *(const f32x4*)&bih[c];
    f32x4 bh = *(const f32x4*)&bhh[c];
    bias[m] = bi + bh;
  }

  const float* xrow = x + (size_t)(16 * blk + lr) * (TSTEPS * NIN);

  for (int j = 0; j < 32; ++j) {
    const int t = tc * 32 + j;
    f32x4 acc[4];
    #pragma unroll
    for (int m = 0; m < 4; ++m) acc[m] = bias[m];
    #pragma unroll
    for (int s = 0; s < 2; ++s) {
      h16x8 bx = cvt8(xrow + (size_t)t * NIN + 32 * s + 8 * lk);
      #pragma unroll
      for (int m = 0; m < 4; ++m)
        acc[m] = __builtin_amdgcn_mfma_f32_16x16x32_f16(A[m][s], bx, acc[m], 0, 0, 0);
    }
    h16x8 c0v, c1v;
    #pragma unroll
    for (int i = 0; i < 4; ++i) {
      c0v[i]     = (h16)acc[0][i];
      c0v[4 + i] = (h16)acc[1][i];
      c1v[i]     = (h16)acc[2][i];
      c1v[4 + i] = (h16)acc[3][i];
    }
    h16* p = xp + ((((size_t)t * 16 + blk) * 8 + wave) * 64 + lane) * 16;
    *(h16x8*)p       = c0v;
    *(h16x8*)(p + 8) = c1v;
  }
}

// ---------------- Path A: recurrence (r9 core + peeled tail) -----------------
__global__ __launch_bounds__(512, 2)
void rnn_core8(const float* __restrict__ Whh, const h16* __restrict__ xp,
               h16* __restrict__ hall)
{
  __shared__ h16 hbuf[2][BB * HPAD];        // 33280 B
  __shared__ h16 aslice[NLDS * 8 * 512];    // 114688 B -> total 147968 B

  const int tid  = threadIdx.x;
  const int wave = tid >> 6;
  const int lane = tid & 63;
  const int lr   = lane & 15;
  const int lk   = lane >> 4;
  const int blk  = blockIdx.x;
  const int b0   = blk * BB;
  const int wc0  = wave * 64;

  // W_hh fragments: slot id = s*4+m; id < NREG -> regs, else LDS
  h16x8 areg[NREG];
  #pragma unroll
  for (int s = 0; s < 16; ++s) {
    #pragma unroll
    for (int m = 0; m < 4; ++m) {
      h16x8 a = cvt8(Whh + (size_t)(wc0 + 16 * m + lr) * HDIM + 32 * s + 8 * lk);
      const int id = s * 4 + m;
      if (id < NREG) areg[id] = a;
      else *(h16x8*)&aslice[(size_t)((id - NREG) * 8 + wave) * 512 + lane * 8] = a;
    }
  }

  for (int idx = tid; idx < BB * HPAD; idx += 512) hbuf[0][idx] = (h16)0.f;
  __syncthreads();   // prologue (once)

  // strength-reduced streaming pointers
  const size_t XSTR = (size_t)16 * 8 * 64 * 16;       // h16 per t-plane
  const size_t HSTR = (size_t)256 * HDIM;             // h16 per t-plane of hall
  const h16* xpp  = xp + (((size_t)blk * 8 + wave) * 64 + lane) * 16;   // t=0
  h16*       hrow = hall + ((size_t)b0 + lr) * HDIM + wc0 + lk * 4;     // t=0

  // preload xp(0)
  h16x8 xr0 = *(const h16x8*)xpp;
  h16x8 xr1 = *(const h16x8*)(xpp + 8);

  for (int t = 0; t < TSTEPS; ++t) {
    const h16* hb = hbuf[t & 1];
    h16*       hn = hbuf[(t + 1) & 1];

    f32x4 acc[4];
    #pragma unroll
    for (int i = 0; i < 4; ++i) {
      acc[0][i] = (float)xr0[i];
      acc[1][i] = (float)xr0[4 + i];
      acc[2][i] = (float)xr1[i];
      acc[3][i] = (float)xr1[4 + i];
    }

    // prefetch xp(t+1); at t=511 this over-reads into hall (mapped, unused)
    xpp += XSTR;
    xr0 = *(const h16x8*)xpp;
    xr1 = *(const h16x8*)(xpp + 8);

    // s = 0..14: bulk MFMA accumulation
    #pragma unroll
    for (int s = 0; s < 15; ++s) {
      h16x8 bh = *(const h16x8*)&hb[lr * HPAD + 32 * s + 8 * lk];
      #pragma unroll
      for (int m = 0; m < 4; ++m) {
        const int id = s * 4 + m;
        h16x8 a = (id < NREG)
            ? areg[id]
            : *(const h16x8*)&aslice[(size_t)((id - NREG) * 8 + wave) * 512 + lane * 8];
        acc[m] = __builtin_amdgcn_mfma_f32_16x16x32_f16(a, bh, acc[m], 0, 0, 0);
      }
    }

    // s = 15 peeled: interleave final MFMA / tanh / writes per m so the
    // tanh+write tail of m overlaps the MFMA latency of m+1.
    {
      h16x8 bh = *(const h16x8*)&hb[lr * HPAD + 32 * 15 + 8 * lk];
      #pragma unroll
      for (int m = 0; m < 4; ++m) {
        const int id = 15 * 4 + m;
        h16x8 a = (id < NREG)
            ? areg[id]
            : *(const h16x8*)&aslice[(size_t)((id - NREG) * 8 + wave) * 512 + lane * 8];
        acc[m] = __builtin_amdgcn_mfma_f32_16x16x32_f16(a, bh, acc[m], 0, 0, 0);
      }
      #pragma unroll
      for (int m = 0; m < 4; ++m) {
        h16x4 hv;
        #pragma unroll
        for (int i = 0; i < 4; ++i) hv[i] = (h16)fast_tanh(acc[m][i]);
        *(h16x4*)&hn[lr * HPAD + wc0 + 16 * m + 4 * lk] = hv;   // LDS handoff
        *(h16x4*)(hrow + 16 * m) = hv;                          // fire-and-forget
      }
    }
    hrow += HSTR;

    // split barrier: drain LDS only (h handoff), not global-store acks
    asm volatile("s_waitcnt lgkmcnt(0)\n\ts_barrier" ::: "memory");
  }
}

// ---------------- Epilogue: out = tanh(h_all @ W_ho^T + b_ho) ----------------
__global__ __launch_bounds__(512)
void out_all(const h16* __restrict__ hall, const float* __restrict__ Who,
             const float* __restrict__ bho, float* __restrict__ out)
{
  __shared__ h16 wholds[NOUT * HPAD];   // 24960 B

  const int tid  = threadIdx.x;
  const int wave = tid >> 6;
  const int lane = tid & 63;
  const int lr   = lane & 15;
  const int lk   = lane >> 4;

  for (int idx = tid; idx < NOUT * HDIM; idx += 512) {
    int r = idx >> 9, k = idx & 511;
    wholds[r * HPAD + k] = (h16)Who[idx];
  }

  f32x4 o0, o1;
  { o0 = *(const f32x4*)&bho[lk * 4]; }
  { int ob = 16 + lk * 4;
    if (ob < NOUT) o1 = *(const f32x4*)&bho[ob];
    else { o1[0] = 0.f; o1[1] = 0.f; o1[2] = 0.f; o1[3] = 0.f; } }
  __syncthreads();

  const int rt = blockIdx.x * 8 + wave;
  const int t  = rt >> 4;
  const int b  = (rt & 15) * 16 + lr;
  const int row1 = (16 + lr < NOUT) ? (16 + lr) : (8 + lr);

  const h16* hrow = hall + ((size_t)t * 256 + b) * HDIM + lk * 8;

  #pragma unroll
  for (int s = 0; s < 16; ++s) {
    h16x8 bh = *(const h16x8*)(hrow + 32 * s);
    h16x8 a0 = *(const h16x8*)&wholds[lr * HPAD + s * 32 + lk * 8];
    h16x8 a1 = *(const h16x8*)&wholds[row1 * HPAD + s * 32 + lk * 8];
    o0 = __builtin_amdgcn_mfma_f32_16x16x32_f16(a0, bh, o0, 0, 0, 0);
    o1 = __builtin_amdgcn_mfma_f32_16x16x32_f16(a1, bh, o1, 0, 0, 0);
  }

  float* op = out + ((size_t)b * TSTEPS + t) * NOUT;
  f32x4 v0;
  #pragma unroll
  for (int i = 0; i < 4; ++i) v0[i] = fast_tanh(o0[i]);
  *(f32x4*)(op + lk * 4) = v0;
  if (lk < 2) {
    f32x4 v1;
    #pragma unroll
    for (int i = 0; i < 4; ++i) v1[i] = fast_tanh(o1[i]);
    *(f32x4*)(op + 16 + lk * 4) = v1;
  }
}

// ---------------- Path C: fully self-contained fallback ----------------------
__device__ __forceinline__ void out_proj(
    int t, const h16* __restrict__ hb, const h16* __restrict__ who,
    f32x4 bho0, f32x4 bho1, float* __restrict__ out, int b0, int lr, int lk)
{
  f32x4 o0 = bho0, o1 = bho1;
  const int row1 = (16 + lr < NOUT) ? (16 + lr) : (8 + lr);
  #pragma unroll
  for (int s = 0; s < 16; ++s) {
    h16x8 bh = *(const h16x8*)&hb[lr * HPAD + s * 32 + lk * 8];
    h16x8 a0 = *(const h16x8*)&who[lr * HPAD + s * 32 + lk * 8];
    h16x8 a1 = *(const h16x8*)&who[row1 * HPAD + s * 32 + lk * 8];
    o0 = __builtin_amdgcn_mfma_f32_16x16x32_f16(a0, bh, o0, 0, 0, 0);
    o1 = __builtin_amdgcn_mfma_f32_16x16x32_f16(a1, bh, o1, 0, 0, 0);
  }
  float* op = out + ((size_t)(b0 + lr) * TSTEPS + t) * NOUT;
  f32x4 v0;
  #pragma unroll
  for (int i = 0; i < 4; ++i) v0[i] = fast_tanh(o0[i]);
  *(f32x4*)(op + lk * 4) = v0;
  if (lk < 2) {
    f32x4 v1;
    #pragma unroll
    for (int i = 0; i < 4; ++i) v1[i] = fast_tanh(o1[i]);
    *(f32x4*)(op + 16 + lk * 4) = v1;
  }
}

__global__ __launch_bounds__(512, 2)
void rnn_fused(const float* __restrict__ x,
               const float* __restrict__ Wih,
               const float* __restrict__ Whh,
               const float* __restrict__ bih,
               const float* __restrict__ bhh,
               const float* __restrict__ Who,
               const float* __restrict__ bho,
               float* __restrict__ out)
{
  __shared__ h16 hbuf[2][BB * HPAD];
  __shared__ h16 xbuf[2][BB * XPAD];
  __shared__ h16 wholds[NOUT * HPAD];

  const int tid  = threadIdx.x;
  const int wave = tid >> 6;
  const int lane = tid & 63;
  const int lr   = lane & 15;
  const int lk   = lane >> 4;
  const int b0   = blockIdx.x * BB;
  const int wc0  = wave * 64;

  h16x8 a_rec[4][16];
  #pragma unroll
  for (int m = 0; m < 4; ++m) {
    const int row = wc0 + m * 16 + lr;
    #pragma unroll
    for (int s = 0; s < 16; ++s)
      a_rec[m][s] = cvt8(Whh + (size_t)row * HDIM + s * 32 + lk * 8);
  }
  h16x8 a_ih[4][2];
  #pragma unroll
  for (int m = 0; m < 4; ++m) {
    const int row = wc0 + m * 16 + lr;
    #pragma unroll
    for (int s = 0; s < 2; ++s)
      a_ih[m][s] = cvt8(Wih + (size_t)row * NIN + s * 32 + lk * 8);
  }
  f32x4 biasv[4];
  #pragma unroll
  for (int m = 0; m < 4; ++m) {
    const int c = wc0 + m * 16 + lk * 4;
    f32x4 bi = *(const f32x4*)&bih[c];
    f32x4 bh2 = *(const f32x4*)&bhh[c];
    biasv[m] = bi + bh2;
  }
  f32x4 bho0, bho1;
  { bho0 = *(const f32x4*)&bho[lk * 4]; }
  { int ob = 16 + lk * 4;
    if (ob < NOUT) bho1 = *(const f32x4*)&bho[ob];
    else { bho1[0] = 0.f; bho1[1] = 0.f; bho1[2] = 0.f; bho1[3] = 0.f; } }

  for (int idx = tid; idx < NOUT * HDIM; idx += 512) {
    int r = idx >> 9, k = idx & 511;
    wholds[r * HPAD + k] = (h16)Who[idx];
  }
  for (int idx = tid; idx < BB * HPAD; idx += 512) hbuf[0][idx] = (h16)0.f;
  {
    int r = tid >> 5, c2 = (tid & 31) * 2;
    f32x2 v = *(const f32x2*)(x + ((size_t)(b0 + r) * TSTEPS + 0) * NIN + c2);
    h16x2 pk = { (h16)v.x, (h16)v.y };
    *(h16x2*)&xbuf[0][r * XPAD + c2] = pk;
  }
  __syncthreads();

  for (int t = 0; t < TSTEPS; ++t) {
    const h16* hb = hbuf[t & 1];
    h16*       hn = hbuf[(t + 1) & 1];
    const h16* xb = xbuf[t & 1];
    h16*       xn = xbuf[(t + 1) & 1];

    if (t > 0 && wave == ((t - 1) & 7))
      out_proj(t - 1, hb, wholds, bho0, bho1, out, b0, lr, lk);

    const int tl = (t + 1 < TSTEPS) ? (t + 1) : (TSTEPS - 1);
    const int xr = tid >> 5, xc = (tid & 31) * 2;
    f32x2 xv = *(const f32x2*)(x + ((size_t)(b0 + xr) * TSTEPS + tl) * NIN + xc);

    f32x4 acc[4];
    #pragma unroll
    for (int m = 0; m < 4; ++m) acc[m] = biasv[m];
    #pragma unroll
    for (int s = 0; s < 2; ++s) {
      h16x8 bx = *(const h16x8*)&xb[lr * XPAD + s * 32 + lk * 8];
      #pragma unroll
      for (int m = 0; m < 4; ++m)
        acc[m] = __builtin_amdgcn_mfma_f32_16x16x32_f16(a_ih[m][s], bx, acc[m], 0, 0, 0);
    }
    #pragma unroll
    for (int s = 0; s < 16; ++s) {
      h16x8 bh = *(const h16x8*)&hb[lr * HPAD + 32 * s + 8 * lk];
      #pragma unroll
      for (int m = 0; m < 4; ++m)
        acc[m] = __builtin_amdgcn_mfma_f32_16x16x32_f16(a_rec[m][s], bh, acc[m], 0, 0, 0);
    }
    #pragma unroll
    for (int m = 0; m < 4; ++m) {
      h16x4 hv;
      #pragma unroll
      for (int i = 0; i < 4; ++i) hv[i] = (h16)fast_tanh(acc[m][i]);
      *(h16x4*)&hn[lr * HPAD + wc0 + 16 * m + 4 * lk] = hv;
    }
    {
      h16x2 pk = { (h16)xv.x, (h16)xv.y };
      *(h16x2*)&xn[xr * XPAD + xc] = pk;
    }
    __syncthreads();
  }

  if (wave == ((TSTEPS - 1) & 7))
    out_proj(TSTEPS - 1, hbuf[TSTEPS & 1], wholds, bho0, bho1, out, b0, lr, lk);
}

extern "C" void kernel_launch(void* const* d_in, const int* in_sizes, int n_in,
                              void* d_out, int out_size, void* d_ws, size_t ws_size,
                              hipStream_t stream) {
  (void)in_sizes; (void)n_in; (void)out_size;
  const float* x   = (const float*)d_in[0];
  const float* Wih = (const float*)d_in[1];
  const float* Whh = (const float*)d_in[2];
  const float* bih = (const float*)d_in[3];
  const float* bhh = (const float*)d_in[4];
  const float* Who = (const float*)d_in[5];
  const float* bho = (const float*)d_in[6];
  float* out = (float*)d_out;

  const size_t XP_BYTES   = (size_t)TSTEPS * 256 * HDIM * sizeof(h16);  // 128 MiB
  const size_t HALL_BYTES = (size_t)TSTEPS * 256 * HDIM * sizeof(h16);  // 128 MiB

  if (ws_size >= XP_BYTES + HALL_BYTES) {
    h16* xp   = (h16*)d_ws;
    h16* hall = (h16*)((char*)d_ws + XP_BYTES);
    xp_gemm<<<dim3(256), dim3(512), 0, stream>>>(x, Wih, bih, bhh, xp);
    rnn_core8<<<dim3(16), dim3(512), 0, stream>>>(Whh, xp, hall);
    out_all<<<dim3(1024), dim3(512), 0, stream>>>(hall, Who, bho, out);
  } else {
    rnn_fused<<<dim3(256 / BB), dim3(512), 0, stream>>>(x, Wih, Whh, bih, bhh, Who, bho, out);
  }
}